// Round 15
// baseline (683.688 us; speedup 1.0000x reference)
//
#include <hip/hip_runtime.h>

#define NN 150000
#define NE 600000
#define NG 5000
#define H 128
#define NOFF (NN + 1)
#define NBLK 147   // ceil(150001 / 1024)
#define NSPLIT 64  // stats_part split factor

typedef short bf16x8 __attribute__((ext_vector_type(8)));
typedef float f32x4 __attribute__((ext_vector_type(4)));

__device__ __forceinline__ unsigned short f2bf(float f) {
    unsigned u = __builtin_bit_cast(unsigned, f);
    u += 0x7fffu + ((u >> 16) & 1u);
    return (unsigned short)(u >> 16);
}
__device__ __forceinline__ float bf2f(unsigned short u) {
    return __builtin_bit_cast(float, (unsigned)u << 16);
}
__device__ __forceinline__ float bflo(unsigned u) {
    return __builtin_bit_cast(float, u << 16);
}
__device__ __forceinline__ float bfhi(unsigned u) {
    return __builtin_bit_cast(float, u & 0xffff0000u);
}
__device__ __forceinline__ unsigned packbf(float lo, float hi) {
    return (unsigned)f2bf(lo) | ((unsigned)f2bf(hi) << 16);
}

// h = bf16(x @ Wn + bn_b), 4 cols/thread
__global__ __launch_bounds__(256) void encoder_k(const float* __restrict__ x,
                                                 const float* __restrict__ Wn,
                                                 const float* __restrict__ bn_b,
                                                 unsigned short* __restrict__ h) {
    int t = blockIdx.x * 256 + threadIdx.x;   // over NN*32
    int i = t >> 5, q = t & 31;
    float4 acc = ((const float4*)bn_b)[q];
#pragma unroll
    for (int k = 0; k < 6; k++) {
        float xv = x[i * 6 + k];
        float4 wv = ((const float4*)Wn)[k * 32 + q];
        acc.x += xv * wv.x; acc.y += xv * wv.y; acc.z += xv * wv.z; acc.w += xv * wv.w;
    }
    ushort4 o;
    o.x = f2bf(acc.x); o.y = f2bf(acc.y); o.z = f2bf(acc.z); o.w = f2bf(acc.w);
    ((ushort4*)h)[t] = o;
}

// ---------- fused setup: zero deg + graph bounds + weight prepack ----------
__global__ __launch_bounds__(256) void setup_k(const int* __restrict__ batch,
                                               const float* __restrict__ W1,
                                               const float* __restrict__ W2,
                                               const float* __restrict__ Wo1,
                                               const float* __restrict__ Wo2,
                                               int* __restrict__ deg,
                                               int* __restrict__ gstart,
                                               unsigned short* __restrict__ Wf) {
    int b = blockIdx.x;
    if (b < 586) {
        int i = b * 256 + threadIdx.x;
        if (i < NN) {
            deg[i] = 0;
            int bt = batch[i];
            int prev = (i == 0) ? -1 : batch[i - 1];
            for (int g = prev + 1; g <= bt; g++) gstart[g] = i;
            if (i == NN - 1)
                for (int g = bt + 1; g <= NG; g++) gstart[g] = NN;
        }
        return;
    }
    int m = b - 586;
    const float* W; int ld, col0;
    if (m < 4)       { W = W1 + m * 16384;       ld = 128; col0 = 0; }
    else if (m < 8)  { W = W2 + (m - 4) * 16384; ld = 128; col0 = 0; }
    else if (m == 8) { W = Wo1;                  ld = 128; col0 = 0; }
    else if (m == 9) { W = Wo2;                  ld = 256; col0 = 0; }
    else             { W = Wo2;                  ld = 256; col0 = 128; }
    unsigned short* dst = Wf + m * 16384;
    for (int flat = threadIdx.x; flat < 2048; flat += 256) {
        int c = flat >> 8, kk = (flat >> 6) & 3, lane = flat & 63;
        int n = col0 + c * 16 + (lane & 15);
        int k0 = kk * 32 + (lane >> 4) * 8;
        ushort4 lo, hi;
        lo.x = f2bf(W[(size_t)(k0 + 0) * ld + n]);
        lo.y = f2bf(W[(size_t)(k0 + 1) * ld + n]);
        lo.z = f2bf(W[(size_t)(k0 + 2) * ld + n]);
        lo.w = f2bf(W[(size_t)(k0 + 3) * ld + n]);
        hi.x = f2bf(W[(size_t)(k0 + 4) * ld + n]);
        hi.y = f2bf(W[(size_t)(k0 + 5) * ld + n]);
        hi.z = f2bf(W[(size_t)(k0 + 6) * ld + n]);
        hi.w = f2bf(W[(size_t)(k0 + 7) * ld + n]);
        *(ushort4*)&dst[flat * 8]     = lo;
        *(ushort4*)&dst[flat * 8 + 4] = hi;
    }
}

// ---------- CSR build ----------

__global__ __launch_bounds__(256) void hist_k(const int* __restrict__ ei,
                                              int* __restrict__ deg) {
    int e = blockIdx.x * 256 + threadIdx.x;
    if (e < NE) atomicAdd(&deg[ei[NE + e]], 1);
}

__global__ __launch_bounds__(256) void scan1_k(const int* __restrict__ deg,
                                               int* __restrict__ part,
                                               int* __restrict__ bsum) {
    __shared__ int ls[256];
    int tid = threadIdx.x;
    int base = blockIdx.x * 1024 + tid * 4;
    int v[4], s = 0;
#pragma unroll
    for (int j = 0; j < 4; j++) {
        int idx = base + j;
        v[j] = (idx < NN) ? deg[idx] : 0;
        s += v[j];
    }
    ls[tid] = s;
    __syncthreads();
    for (int off = 1; off < 256; off <<= 1) {
        int t2 = (tid >= off) ? ls[tid - off] : 0;
        __syncthreads();
        if (tid >= off) ls[tid] += t2;
        __syncthreads();
    }
    int run = ls[tid] - s;
#pragma unroll
    for (int j = 0; j < 4; j++) {
        int idx = base + j;
        if (idx < NOFF) part[idx] = run;
        run += v[j];
    }
    if (tid == 255) bsum[blockIdx.x] = ls[255];
}

__global__ __launch_bounds__(256) void scan2_k(int* __restrict__ bsum) {
    __shared__ int ls[256];
    int tid = threadIdx.x;
    int v = (tid < NBLK) ? bsum[tid] : 0;
    ls[tid] = v;
    __syncthreads();
    for (int off = 1; off < 256; off <<= 1) {
        int t2 = (tid >= off) ? ls[tid - off] : 0;
        __syncthreads();
        if (tid >= off) ls[tid] += t2;
        __syncthreads();
    }
    if (tid < NBLK) bsum[tid] = ls[tid] - v;
}

__global__ __launch_bounds__(256) void scan3_k(const int* __restrict__ part,
                                               const int* __restrict__ bsum,
                                               int* __restrict__ offsets,
                                               int* __restrict__ cursor) {
    int tid = threadIdx.x;
    int base = blockIdx.x * 1024 + tid * 4;
    int bs = bsum[blockIdx.x];
#pragma unroll
    for (int j = 0; j < 4; j++) {
        int idx = base + j;
        if (idx < NOFF) {
            int o = part[idx] + bs;
            offsets[idx] = o;
            if (idx < NN) cursor[idx] = o;
        }
    }
}

__global__ __launch_bounds__(256) void fill_k(const int* __restrict__ ei,
                                              int* __restrict__ cursor,
                                              int* __restrict__ adj) {
    int e = blockIdx.x * 256 + threadIdx.x;
    if (e < NE) {
        int p = atomicAdd(&cursor[ei[NE + e]], 1);
        if (p >= 0 && p < NE) adj[p] = ei[e];
    }
}

// ---------- gather: quarter-wave per row, 16 B/lane loads ----------
__global__ __launch_bounds__(256) void gather_k(const unsigned short* __restrict__ h,
                                                const int* __restrict__ offsets,
                                                const int* __restrict__ adj,
                                                const float* __restrict__ eps, int l,
                                                unsigned short* __restrict__ agg,
                                                float* __restrict__ stats_part) {
    int tid = threadIdx.x;
    if (blockIdx.x < NSPLIT) stats_part[blockIdx.x * 256 + tid] = 0.f;
    int wv = tid >> 6, lane = tid & 63;
    int sub = lane >> 4, lr = lane & 15;
    int i = blockIdx.x * 16 + wv * 4 + sub;   // 9375 blocks * 16 rows
    const uint4* hp = (const uint4*)h;        // row = 16 uint4 (256 B)
    float e = 1.f + eps[l];
    uint4 sv = hp[(size_t)i * 16 + lr];
    float a0 = bflo(sv.x) * e, a1 = bfhi(sv.x) * e;
    float a2 = bflo(sv.y) * e, a3 = bfhi(sv.y) * e;
    float a4 = bflo(sv.z) * e, a5 = bfhi(sv.z) * e;
    float a6 = bflo(sv.w) * e, a7 = bfhi(sv.w) * e;
    int s0 = offsets[i], s1 = offsets[i + 1];
    for (int k = s0; k < s1; k++) {
        uint4 v = hp[(size_t)adj[k] * 16 + lr];
        a0 += bflo(v.x); a1 += bfhi(v.x);
        a2 += bflo(v.y); a3 += bfhi(v.y);
        a4 += bflo(v.z); a5 += bfhi(v.z);
        a6 += bflo(v.w); a7 += bfhi(v.w);
    }
    uint4 o;
    o.x = packbf(a0, a1); o.y = packbf(a2, a3);
    o.z = packbf(a4, a5); o.w = packbf(a6, a7);
    ((uint4*)agg)[(size_t)i * 16 + lr] = o;
}

// ---------- fused MLP: m = bf16( relu(agg@W1+b1) @ W2 + b2 ), + BN stats ----------
// 128 rows/block; each wave owns TWO 16-row tiles -> each W fragment (from
// global/L2) feeds 2 independent MFMA chains (2x ILP, half the load:MFMA ratio).
__global__ __launch_bounds__(256) void mlp_k(const unsigned short* __restrict__ A,
                                             const unsigned short* __restrict__ Wf1,
                                             const unsigned short* __restrict__ Wf2,
                                             const float* __restrict__ b1,
                                             const float* __restrict__ b2,
                                             unsigned short* __restrict__ Cm, int M,
                                             float* __restrict__ stats_part) {
    __shared__ short Tlds[128 * 136];  // t tile (128 rows), +8 short pad
    __shared__ float sst[256];
    int tid = threadIdx.x;
    sst[tid] = 0.f;
    __syncthreads();

    int w = tid >> 6, lane = tid & 63;
    int quad = lane >> 4, lr = lane & 15;
    int row0 = blockIdx.x * 128 + w * 32 + lr;        // tile 0
    int row1 = row0 + 16;                             // tile 1
    bool ok0 = row0 < M, ok1 = row1 < M;
    const unsigned short* ap0 = A + (size_t)row0 * 128 + quad * 8;
    const unsigned short* ap1 = A + (size_t)row1 * 128 + quad * 8;
    const bf16x8* w1p = (const bf16x8*)Wf1;
    const bf16x8* w2p = (const bf16x8*)Wf2;

    // phase 1: t = relu(agg @ W1 + b1), W1 from global/L2, shared by both tiles
    f32x4 acc0[8], acc1[8];
#pragma unroll
    for (int c = 0; c < 8; c++) {
        acc0[c] = (f32x4){0.f, 0.f, 0.f, 0.f};
        acc1[c] = (f32x4){0.f, 0.f, 0.f, 0.f};
    }
#pragma unroll
    for (int kk = 0; kk < 4; kk++) {
        bf16x8 af0 = ok0 ? *(const bf16x8*)(ap0 + kk * 32)
                         : (bf16x8){0, 0, 0, 0, 0, 0, 0, 0};
        bf16x8 af1 = ok1 ? *(const bf16x8*)(ap1 + kk * 32)
                         : (bf16x8){0, 0, 0, 0, 0, 0, 0, 0};
#pragma unroll
        for (int c = 0; c < 8; c++) {
            bf16x8 bf = w1p[(c * 4 + kk) * 64 + lane];
            acc0[c] = __builtin_amdgcn_mfma_f32_16x16x32_bf16(af0, bf, acc0[c], 0, 0, 0);
            acc1[c] = __builtin_amdgcn_mfma_f32_16x16x32_bf16(af1, bf, acc1[c], 0, 0, 0);
        }
    }
    // write both t-tiles to own wave's LDS slice (within-wave handoff, no barrier)
    int rl0 = w * 32 + quad * 4;
#pragma unroll
    for (int c = 0; c < 8; c++) {
        int col = c * 16 + lr;
        float bv = b1[col];
#pragma unroll
        for (int r = 0; r < 4; r++) {
            Tlds[(rl0 + r) * 136 + col]      = (short)f2bf(fmaxf(acc0[c][r] + bv, 0.f));
            Tlds[(rl0 + 16 + r) * 136 + col] = (short)f2bf(fmaxf(acc1[c][r] + bv, 0.f));
        }
    }

    // phase 2: m = t @ W2 + b2
#pragma unroll
    for (int c = 0; c < 8; c++) {
        acc0[c] = (f32x4){0.f, 0.f, 0.f, 0.f};
        acc1[c] = (f32x4){0.f, 0.f, 0.f, 0.f};
    }
#pragma unroll
    for (int kk = 0; kk < 4; kk++) {
        bf16x8 af0 = *(const bf16x8*)&Tlds[(w * 32 + lr) * 136 + kk * 32 + quad * 8];
        bf16x8 af1 = *(const bf16x8*)&Tlds[(w * 32 + 16 + lr) * 136 + kk * 32 + quad * 8];
#pragma unroll
        for (int c = 0; c < 8; c++) {
            bf16x8 bf = w2p[(c * 4 + kk) * 64 + lane];
            acc0[c] = __builtin_amdgcn_mfma_f32_16x16x32_bf16(af0, bf, acc0[c], 0, 0, 0);
            acc1[c] = __builtin_amdgcn_mfma_f32_16x16x32_bf16(af1, bf, acc1[c], 0, 0, 0);
        }
    }

    int r0 = blockIdx.x * 128 + w * 32 + quad * 4;
#pragma unroll
    for (int c = 0; c < 8; c++) {
        int col = c * 16 + lr;
        float bv = b2[col];
        float ls = 0.f, ls2 = 0.f;
#pragma unroll
        for (int r = 0; r < 4; r++) {
            int row = r0 + r;
            if (row < M) {
                float v = acc0[c][r] + bv;
                Cm[(size_t)row * H + col] = f2bf(v);
                ls += v; ls2 += v * v;
            }
            int rowb = r0 + 16 + r;
            if (rowb < M) {
                float v = acc1[c][r] + bv;
                Cm[(size_t)rowb * H + col] = f2bf(v);
                ls += v; ls2 += v * v;
            }
        }
        ls  += __shfl_xor(ls, 16);  ls  += __shfl_xor(ls, 32);
        ls2 += __shfl_xor(ls2, 16); ls2 += __shfl_xor(ls2, 32);
        if (quad == 0) {
            atomicAdd(&sst[col], ls);
            atomicAdd(&sst[128 + col], ls2);
        }
    }
    __syncthreads();
    atomicAdd(&stats_part[(blockIdx.x & (NSPLIT - 1)) * 256 + tid], sst[tid]);
}

// reduce stats_part -> coef[c]=gamma*istd, coef[128+c]=beta-mu*gamma*istd
__global__ __launch_bounds__(256) void finalize_stats_k(const float* __restrict__ stats_part,
                                                        const float* __restrict__ gamma,
                                                        const float* __restrict__ beta,
                                                        float* __restrict__ coef, float invN) {
    __shared__ float ls[256];
    int t = threadIdx.x;
    float s = 0.f;
    for (int p = 0; p < NSPLIT; p++) s += stats_part[p * 256 + t];
    ls[t] = s;
    __syncthreads();
    if (t < 128) {
        float mu = ls[t] * invN;
        float var = ls[128 + t] * invN - mu * mu;
        float a = gamma[t] * rsqrtf(var + 1e-5f);
        coef[t] = a;
        coef[128 + t] = beta[t] - mu * a;
    }
}

// C[M,128] = op(bf16 A[M,128] @ Wf + bias)
template <bool RELU, bool OBF16>
__global__ __launch_bounds__(256) void gemm128f(const unsigned short* __restrict__ A,
                                                const unsigned short* __restrict__ Wf,
                                                const float* __restrict__ bias,
                                                void* __restrict__ Cv, int ldC, int M) {
    __shared__ short Wlds[16384];
    int tid = threadIdx.x;
#pragma unroll
    for (int i = 0; i < 8; i++) {
        int flat = i * 256 + tid;
        ((bf16x8*)Wlds)[flat] = ((const bf16x8*)Wf)[flat];
    }
    __syncthreads();

    int w = tid >> 6, lane = tid & 63;
    int quad = lane >> 4, lr = lane & 15;
    int rowA = blockIdx.x * 64 + w * 16 + lr;
    bool rowOK = rowA < M;
    const unsigned short* ap = A + (size_t)rowA * 128 + quad * 8;

    f32x4 acc[8];
#pragma unroll
    for (int c = 0; c < 8; c++) acc[c] = (f32x4){0.f, 0.f, 0.f, 0.f};
#pragma unroll
    for (int kk = 0; kk < 4; kk++) {
        bf16x8 af = rowOK ? *(const bf16x8*)(ap + kk * 32)
                          : (bf16x8){0, 0, 0, 0, 0, 0, 0, 0};
#pragma unroll
        for (int c = 0; c < 8; c++) {
            bf16x8 bf = ((const bf16x8*)Wlds)[(c * 4 + kk) * 64 + lane];
            acc[c] = __builtin_amdgcn_mfma_f32_16x16x32_bf16(af, bf, acc[c], 0, 0, 0);
        }
    }

    int r0 = blockIdx.x * 64 + w * 16 + quad * 4;
#pragma unroll
    for (int c = 0; c < 8; c++) {
        int col = c * 16 + lr;
        float bv = bias[col];
#pragma unroll
        for (int r = 0; r < 4; r++) {
            int row = r0 + r;
            if (row < M) {
                float v = acc[c][r] + bv;
                if (RELU) v = fmaxf(v, 0.f);
                if (OBF16)
                    ((unsigned short*)Cv)[(size_t)row * ldC + col] = f2bf(v);
                else
                    ((float*)Cv)[(size_t)row * ldC + col] = v;
            }
        }
    }
}

// both Wo2 halves in one launch: blocks [0,79) half 0, [79,158) half 1
__global__ __launch_bounds__(256) void outproj2_k(const unsigned short* __restrict__ A,
                                                  const unsigned short* __restrict__ WfB,
                                                  const float* __restrict__ bo2,
                                                  float* __restrict__ out) {
    __shared__ short Wlds[16384];
    int half = blockIdx.x >= 79;
    int blk = blockIdx.x - half * 79;
    const unsigned short* Wf = WfB + half * 16384;
    int tid = threadIdx.x;
#pragma unroll
    for (int i = 0; i < 8; i++) {
        int flat = i * 256 + tid;
        ((bf16x8*)Wlds)[flat] = ((const bf16x8*)Wf)[flat];
    }
    __syncthreads();

    int w = tid >> 6, lane = tid & 63;
    int quad = lane >> 4, lr = lane & 15;
    int rowA = blk * 64 + w * 16 + lr;
    bool rowOK = rowA < NG;
    const unsigned short* ap = A + (size_t)rowA * 128 + quad * 8;

    f32x4 acc[8];
#pragma unroll
    for (int c = 0; c < 8; c++) acc[c] = (f32x4){0.f, 0.f, 0.f, 0.f};
#pragma unroll
    for (int kk = 0; kk < 4; kk++) {
        bf16x8 af = rowOK ? *(const bf16x8*)(ap + kk * 32)
                          : (bf16x8){0, 0, 0, 0, 0, 0, 0, 0};
#pragma unroll
        for (int c = 0; c < 8; c++) {
            bf16x8 bf = ((const bf16x8*)Wlds)[(c * 4 + kk) * 64 + lane];
            acc[c] = __builtin_amdgcn_mfma_f32_16x16x32_bf16(af, bf, acc[c], 0, 0, 0);
        }
    }

    int r0 = blk * 64 + w * 16 + quad * 4;
#pragma unroll
    for (int c = 0; c < 8; c++) {
        int col = half * 128 + c * 16 + lr;
        float bv = bo2[col];
#pragma unroll
        for (int r = 0; r < 4; r++) {
            int row = r0 + r;
            if (row < NG) out[(size_t)row * 256 + col] = acc[c][r] + bv;
        }
    }
}

// h = bf16(relu(m*a + b) + h)
__global__ __launch_bounds__(256) void bn_apply_k(const unsigned short* __restrict__ m,
                                                  const float* __restrict__ coef,
                                                  unsigned short* __restrict__ h) {
    int t = blockIdx.x * 256 + threadIdx.x;   // NN*32
    int c4 = t & 31;
    float4 a = ((const float4*)coef)[c4];
    float4 b = ((const float4*)coef)[32 + c4];
    ushort4 mv = ((const ushort4*)m)[t];
    ushort4 hv = ((const ushort4*)h)[t];
    float h0 = bf2f(hv.x) + fmaxf(bf2f(mv.x) * a.x + b.x, 0.f);
    float h1 = bf2f(hv.y) + fmaxf(bf2f(mv.y) * a.y + b.y, 0.f);
    float h2 = bf2f(hv.z) + fmaxf(bf2f(mv.z) * a.z + b.z, 0.f);
    float h3 = bf2f(hv.w) + fmaxf(bf2f(mv.w) * a.w + b.w, 0.f);
    ushort4 o;
    o.x = f2bf(h0); o.y = f2bf(h1); o.z = f2bf(h2); o.w = f2bf(h3);
    ((ushort4*)h)[t] = o;
}

// one block per graph: mean over its node rows -> bf16 pooled
__global__ __launch_bounds__(128) void pool_k(const unsigned short* __restrict__ h,
                                              const int* __restrict__ gstart,
                                              unsigned short* __restrict__ pooled) {
    int g = blockIdx.x, col = threadIdx.x;
    int r0 = gstart[g], r1 = gstart[g + 1];
    float s = 0.f;
    for (int r = r0; r < r1; r++) s += bf2f(h[(size_t)r * H + col]);
    pooled[(size_t)g * H + col] = f2bf(s / fmaxf((float)(r1 - r0), 1.f));
}

extern "C" void kernel_launch(void* const* d_in, const int* in_sizes, int n_in,
                              void* d_out, int out_size, void* d_ws, size_t ws_size,
                              hipStream_t stream) {
    const float* x     = (const float*)d_in[0];
    const int*   ei    = (const int*)d_in[1];
    const int*   batch = (const int*)d_in[2];
    const float* Wn    = (const float*)d_in[3];
    const float* bn_b  = (const float*)d_in[4];
    const float* eps   = (const float*)d_in[5];
    const float* W1    = (const float*)d_in[6];
    const float* b1    = (const float*)d_in[7];
    const float* W2    = (const float*)d_in[8];
    const float* b2    = (const float*)d_in[9];
    const float* gamma = (const float*)d_in[10];
    const float* beta  = (const float*)d_in[11];
    const float* Wo1   = (const float*)d_in[12];
    const float* bo1   = (const float*)d_in[13];
    const float* Wo2   = (const float*)d_in[14];
    const float* bo2   = (const float*)d_in[15];
    float* out = (float*)d_out;

    // ---- workspace: ~120 MB ----
    unsigned short* h    = (unsigned short*)d_ws;                  // NN*H bf16
    unsigned short* m    = h + (size_t)NN * H;                     // NN*H bf16
    unsigned short* aggB = m + (size_t)NN * H;                     // NN*H bf16
    unsigned short* tB   = aggB + (size_t)NN * H;                  // NG*H bf16
    float* stats_part    = (float*)(tB + (size_t)NG * H);          // NSPLIT*256
    float* coef          = stats_part + NSPLIT * 256;              // 256
    unsigned short* Wf   = (unsigned short*)(coef + 256);          // 11*16384 bf16
    unsigned short* pooledB = Wf + 11 * 16384;                     // NG*H bf16
    int* offsets = (int*)(pooledB + (size_t)NG * H);               // NOFF
    int* adj     = offsets + NOFF;                                 // NE
    int* gstart  = adj + NE;                                       // NG+1
    // transient CSR-build arrays overlaid in m (first written by layer-0 mlp_k)
    int* deg    = (int*)m;         // NN
    int* part   = deg + NN;        // NOFF
    int* bsum   = part + NOFF;     // 256
    int* cursor = bsum + 256;      // NN

    setup_k<<<597, 256, 0, stream>>>(batch, W1, W2, Wo1, Wo2, deg, gstart, Wf);
    hist_k<<<2344, 256, 0, stream>>>(ei, deg);
    scan1_k<<<NBLK, 256, 0, stream>>>(deg, part, bsum);
    scan2_k<<<1, 256, 0, stream>>>(bsum);
    scan3_k<<<NBLK, 256, 0, stream>>>(part, bsum, offsets, cursor);
    fill_k<<<2344, 256, 0, stream>>>(ei, cursor, adj);

    encoder_k<<<18750, 256, 0, stream>>>(x, Wn, bn_b, h);

    for (int l = 0; l < 4; l++) {
        gather_k<<<9375, 256, 0, stream>>>(h, offsets, adj, eps, l, aggB, stats_part);
        mlp_k<<<1172, 256, 0, stream>>>(aggB, Wf + l * 16384, Wf + (4 + l) * 16384,
                                        b1 + l * 128, b2 + l * 128, m, NN, stats_part);
        finalize_stats_k<<<1, 256, 0, stream>>>(stats_part, gamma + l * 128,
                                                beta + l * 128, coef, 1.f / NN);
        bn_apply_k<<<18750, 256, 0, stream>>>(m, coef, h);
    }

    pool_k<<<NG, 128, 0, stream>>>(h, gstart, pooledB);

    gemm128f<true, true><<<79, 256, 0, stream>>>(
        pooledB, Wf + 8 * 16384, bo1, tB, 128, NG);
    outproj2_k<<<158, 256, 0, stream>>>(tB, Wf + 9 * 16384, bo2, out);
}

// Round 16
// 627.585 us; speedup vs baseline: 1.0894x; 1.0894x over previous
//
#include <hip/hip_runtime.h>

#define NN 150000
#define NE 600000
#define NG 5000
#define H 128
#define NOFF (NN + 1)
#define NBLK 147   // ceil(150001 / 1024)
#define NSPLIT 64  // stats_part split factor

typedef short bf16x8 __attribute__((ext_vector_type(8)));
typedef float f32x4 __attribute__((ext_vector_type(4)));

__device__ __forceinline__ unsigned short f2bf(float f) {
    unsigned u = __builtin_bit_cast(unsigned, f);
    u += 0x7fffu + ((u >> 16) & 1u);
    return (unsigned short)(u >> 16);
}
__device__ __forceinline__ float bf2f(unsigned short u) {
    return __builtin_bit_cast(float, (unsigned)u << 16);
}
__device__ __forceinline__ float bflo(unsigned u) {
    return __builtin_bit_cast(float, u << 16);
}
__device__ __forceinline__ float bfhi(unsigned u) {
    return __builtin_bit_cast(float, u & 0xffff0000u);
}
__device__ __forceinline__ unsigned packbf(float lo, float hi) {
    return (unsigned)f2bf(lo) | ((unsigned)f2bf(hi) << 16);
}

// h = bf16(x @ Wn + bn_b), 4 cols/thread
__global__ __launch_bounds__(256) void encoder_k(const float* __restrict__ x,
                                                 const float* __restrict__ Wn,
                                                 const float* __restrict__ bn_b,
                                                 unsigned short* __restrict__ h) {
    int t = blockIdx.x * 256 + threadIdx.x;   // over NN*32
    int i = t >> 5, q = t & 31;
    float4 acc = ((const float4*)bn_b)[q];
#pragma unroll
    for (int k = 0; k < 6; k++) {
        float xv = x[i * 6 + k];
        float4 wv = ((const float4*)Wn)[k * 32 + q];
        acc.x += xv * wv.x; acc.y += xv * wv.y; acc.z += xv * wv.z; acc.w += xv * wv.w;
    }
    ushort4 o;
    o.x = f2bf(acc.x); o.y = f2bf(acc.y); o.z = f2bf(acc.z); o.w = f2bf(acc.w);
    ((ushort4*)h)[t] = o;
}

// ---------- fused setup: zero deg + graph bounds + weight prepack ----------
__global__ __launch_bounds__(256) void setup_k(const int* __restrict__ batch,
                                               const float* __restrict__ W1,
                                               const float* __restrict__ W2,
                                               const float* __restrict__ Wo1,
                                               const float* __restrict__ Wo2,
                                               int* __restrict__ deg,
                                               int* __restrict__ gstart,
                                               unsigned short* __restrict__ Wf) {
    int b = blockIdx.x;
    if (b < 586) {
        int i = b * 256 + threadIdx.x;
        if (i < NN) {
            deg[i] = 0;
            int bt = batch[i];
            int prev = (i == 0) ? -1 : batch[i - 1];
            for (int g = prev + 1; g <= bt; g++) gstart[g] = i;
            if (i == NN - 1)
                for (int g = bt + 1; g <= NG; g++) gstart[g] = NN;
        }
        return;
    }
    int m = b - 586;
    const float* W; int ld, col0;
    if (m < 4)       { W = W1 + m * 16384;       ld = 128; col0 = 0; }
    else if (m < 8)  { W = W2 + (m - 4) * 16384; ld = 128; col0 = 0; }
    else if (m == 8) { W = Wo1;                  ld = 128; col0 = 0; }
    else if (m == 9) { W = Wo2;                  ld = 256; col0 = 0; }
    else             { W = Wo2;                  ld = 256; col0 = 128; }
    unsigned short* dst = Wf + m * 16384;
    for (int flat = threadIdx.x; flat < 2048; flat += 256) {
        int c = flat >> 8, kk = (flat >> 6) & 3, lane = flat & 63;
        int n = col0 + c * 16 + (lane & 15);
        int k0 = kk * 32 + (lane >> 4) * 8;
        ushort4 lo, hi;
        lo.x = f2bf(W[(size_t)(k0 + 0) * ld + n]);
        lo.y = f2bf(W[(size_t)(k0 + 1) * ld + n]);
        lo.z = f2bf(W[(size_t)(k0 + 2) * ld + n]);
        lo.w = f2bf(W[(size_t)(k0 + 3) * ld + n]);
        hi.x = f2bf(W[(size_t)(k0 + 4) * ld + n]);
        hi.y = f2bf(W[(size_t)(k0 + 5) * ld + n]);
        hi.z = f2bf(W[(size_t)(k0 + 6) * ld + n]);
        hi.w = f2bf(W[(size_t)(k0 + 7) * ld + n]);
        *(ushort4*)&dst[flat * 8]     = lo;
        *(ushort4*)&dst[flat * 8 + 4] = hi;
    }
}

// ---------- CSR build ----------

__global__ __launch_bounds__(256) void hist_k(const int* __restrict__ ei,
                                              int* __restrict__ deg) {
    int e = blockIdx.x * 256 + threadIdx.x;
    if (e < NE) atomicAdd(&deg[ei[NE + e]], 1);
}

__global__ __launch_bounds__(256) void scan1_k(const int* __restrict__ deg,
                                               int* __restrict__ part,
                                               int* __restrict__ bsum) {
    __shared__ int ls[256];
    int tid = threadIdx.x;
    int base = blockIdx.x * 1024 + tid * 4;
    int v[4], s = 0;
#pragma unroll
    for (int j = 0; j < 4; j++) {
        int idx = base + j;
        v[j] = (idx < NN) ? deg[idx] : 0;
        s += v[j];
    }
    ls[tid] = s;
    __syncthreads();
    for (int off = 1; off < 256; off <<= 1) {
        int t2 = (tid >= off) ? ls[tid - off] : 0;
        __syncthreads();
        if (tid >= off) ls[tid] += t2;
        __syncthreads();
    }
    int run = ls[tid] - s;
#pragma unroll
    for (int j = 0; j < 4; j++) {
        int idx = base + j;
        if (idx < NOFF) part[idx] = run;
        run += v[j];
    }
    if (tid == 255) bsum[blockIdx.x] = ls[255];
}

__global__ __launch_bounds__(256) void scan2_k(int* __restrict__ bsum) {
    __shared__ int ls[256];
    int tid = threadIdx.x;
    int v = (tid < NBLK) ? bsum[tid] : 0;
    ls[tid] = v;
    __syncthreads();
    for (int off = 1; off < 256; off <<= 1) {
        int t2 = (tid >= off) ? ls[tid - off] : 0;
        __syncthreads();
        if (tid >= off) ls[tid] += t2;
        __syncthreads();
    }
    if (tid < NBLK) bsum[tid] = ls[tid] - v;
}

__global__ __launch_bounds__(256) void scan3_k(const int* __restrict__ part,
                                               const int* __restrict__ bsum,
                                               int* __restrict__ offsets,
                                               int* __restrict__ cursor) {
    int tid = threadIdx.x;
    int base = blockIdx.x * 1024 + tid * 4;
    int bs = bsum[blockIdx.x];
#pragma unroll
    for (int j = 0; j < 4; j++) {
        int idx = base + j;
        if (idx < NOFF) {
            int o = part[idx] + bs;
            offsets[idx] = o;
            if (idx < NN) cursor[idx] = o;
        }
    }
}

__global__ __launch_bounds__(256) void fill_k(const int* __restrict__ ei,
                                              int* __restrict__ cursor,
                                              int* __restrict__ adj) {
    int e = blockIdx.x * 256 + threadIdx.x;
    if (e < NE) {
        int p = atomicAdd(&cursor[ei[NE + e]], 1);
        if (p >= 0 && p < NE) adj[p] = ei[e];
    }
}

// ---------- gather: quarter-wave per row, 16 B/lane, 2x unrolled ----------
__global__ __launch_bounds__(256) void gather_k(const unsigned short* __restrict__ h,
                                                const int* __restrict__ offsets,
                                                const int* __restrict__ adj,
                                                const float* __restrict__ eps, int l,
                                                unsigned short* __restrict__ agg,
                                                float* __restrict__ stats_part) {
    int tid = threadIdx.x;
    if (blockIdx.x < NSPLIT) stats_part[blockIdx.x * 256 + tid] = 0.f;
    int wv = tid >> 6, lane = tid & 63;
    int sub = lane >> 4, lr = lane & 15;
    int i = blockIdx.x * 16 + wv * 4 + sub;   // 9375 blocks * 16 rows
    const uint4* hp = (const uint4*)h;        // row = 16 uint4 (256 B)
    float e = 1.f + eps[l];
    uint4 sv = hp[(size_t)i * 16 + lr];
    float a0 = bflo(sv.x) * e, a1 = bfhi(sv.x) * e;
    float a2 = bflo(sv.y) * e, a3 = bfhi(sv.y) * e;
    float a4 = bflo(sv.z) * e, a5 = bfhi(sv.z) * e;
    float a6 = bflo(sv.w) * e, a7 = bfhi(sv.w) * e;
    float b0 = 0.f, b1 = 0.f, b2 = 0.f, b3 = 0.f;
    float b4 = 0.f, b5 = 0.f, b6 = 0.f, b7 = 0.f;
    int s0 = offsets[i], s1 = offsets[i + 1];
    int k = s0;
    for (; k + 1 < s1; k += 2) {
        int src0 = adj[k], src1 = adj[k + 1];
        uint4 v0 = hp[(size_t)src0 * 16 + lr];
        uint4 v1 = hp[(size_t)src1 * 16 + lr];
        a0 += bflo(v0.x); a1 += bfhi(v0.x);
        a2 += bflo(v0.y); a3 += bfhi(v0.y);
        a4 += bflo(v0.z); a5 += bfhi(v0.z);
        a6 += bflo(v0.w); a7 += bfhi(v0.w);
        b0 += bflo(v1.x); b1 += bfhi(v1.x);
        b2 += bflo(v1.y); b3 += bfhi(v1.y);
        b4 += bflo(v1.z); b5 += bfhi(v1.z);
        b6 += bflo(v1.w); b7 += bfhi(v1.w);
    }
    if (k < s1) {
        uint4 v = hp[(size_t)adj[k] * 16 + lr];
        a0 += bflo(v.x); a1 += bfhi(v.x);
        a2 += bflo(v.y); a3 += bfhi(v.y);
        a4 += bflo(v.z); a5 += bfhi(v.z);
        a6 += bflo(v.w); a7 += bfhi(v.w);
    }
    a0 += b0; a1 += b1; a2 += b2; a3 += b3;
    a4 += b4; a5 += b5; a6 += b6; a7 += b7;
    uint4 o;
    o.x = packbf(a0, a1); o.y = packbf(a2, a3);
    o.z = packbf(a4, a5); o.w = packbf(a6, a7);
    ((uint4*)agg)[(size_t)i * 16 + lr] = o;
}

// ---------- fused MLP (R13-proven): W1/W2 staged in LDS, t-tile in LDS ----------
__global__ __launch_bounds__(256) void mlp_k(const unsigned short* __restrict__ A,
                                             const unsigned short* __restrict__ Wf1,
                                             const unsigned short* __restrict__ Wf2,
                                             const float* __restrict__ b1,
                                             const float* __restrict__ b2,
                                             unsigned short* __restrict__ Cm, int M,
                                             float* __restrict__ stats_part) {
    __shared__ short Wlds[16384];      // fragment-order W (W1, then W2)
    __shared__ short Tlds[64 * 136];   // t tile, +8 short pad
    __shared__ float sst[256];
    int tid = threadIdx.x;
#pragma unroll
    for (int i = 0; i < 8; i++) {
        int flat = i * 256 + tid;
        ((bf16x8*)Wlds)[flat] = ((const bf16x8*)Wf1)[flat];
    }
    sst[tid] = 0.f;
    __syncthreads();

    int w = tid >> 6, lane = tid & 63;
    int quad = lane >> 4, lr = lane & 15;
    int rowA = blockIdx.x * 64 + w * 16 + lr;
    bool rowOK = rowA < M;
    const unsigned short* ap = A + (size_t)rowA * 128 + quad * 8;

    // phase 1: t = relu(agg @ W1 + b1)
    f32x4 acc[8];
#pragma unroll
    for (int c = 0; c < 8; c++) acc[c] = (f32x4){0.f, 0.f, 0.f, 0.f};
#pragma unroll
    for (int kk = 0; kk < 4; kk++) {
        bf16x8 af = rowOK ? *(const bf16x8*)(ap + kk * 32)
                          : (bf16x8){0, 0, 0, 0, 0, 0, 0, 0};
#pragma unroll
        for (int c = 0; c < 8; c++) {
            bf16x8 bf = ((const bf16x8*)Wlds)[(c * 4 + kk) * 64 + lane];
            acc[c] = __builtin_amdgcn_mfma_f32_16x16x32_bf16(af, bf, acc[c], 0, 0, 0);
        }
    }
    int rl0 = w * 16 + quad * 4;
#pragma unroll
    for (int c = 0; c < 8; c++) {
        int col = c * 16 + lr;
        float bv = b1[col];
#pragma unroll
        for (int r = 0; r < 4; r++)
            Tlds[(rl0 + r) * 136 + col] = (short)f2bf(fmaxf(acc[c][r] + bv, 0.f));
    }
    __syncthreads();
#pragma unroll
    for (int i = 0; i < 8; i++) {
        int flat = i * 256 + tid;
        ((bf16x8*)Wlds)[flat] = ((const bf16x8*)Wf2)[flat];
    }
    __syncthreads();

    // phase 2: m = t @ W2 + b2
#pragma unroll
    for (int c = 0; c < 8; c++) acc[c] = (f32x4){0.f, 0.f, 0.f, 0.f};
#pragma unroll
    for (int kk = 0; kk < 4; kk++) {
        bf16x8 af = *(const bf16x8*)&Tlds[(w * 16 + lr) * 136 + kk * 32 + quad * 8];
#pragma unroll
        for (int c = 0; c < 8; c++) {
            bf16x8 bf = ((const bf16x8*)Wlds)[(c * 4 + kk) * 64 + lane];
            acc[c] = __builtin_amdgcn_mfma_f32_16x16x32_bf16(af, bf, acc[c], 0, 0, 0);
        }
    }

    int r0 = blockIdx.x * 64 + w * 16 + quad * 4;
#pragma unroll
    for (int c = 0; c < 8; c++) {
        int col = c * 16 + lr;
        float bv = b2[col];
        float ls = 0.f, ls2 = 0.f;
#pragma unroll
        for (int r = 0; r < 4; r++) {
            int row = r0 + r;
            if (row < M) {
                float v = acc[c][r] + bv;
                Cm[(size_t)row * H + col] = f2bf(v);
                ls += v; ls2 += v * v;
            }
        }
        ls  += __shfl_xor(ls, 16);  ls  += __shfl_xor(ls, 32);
        ls2 += __shfl_xor(ls2, 16); ls2 += __shfl_xor(ls2, 32);
        if (quad == 0) {
            atomicAdd(&sst[col], ls);
            atomicAdd(&sst[128 + col], ls2);
        }
    }
    __syncthreads();
    atomicAdd(&stats_part[(blockIdx.x & (NSPLIT - 1)) * 256 + tid], sst[tid]);
}

// ---------- bn_apply with inline stats->coef reduce (replaces finalize_stats) ----------
// grid-stride (2048 blocks); stride is a multiple of 32 so each thread's
// column quad is loop-invariant -> coef cached in registers.
__global__ __launch_bounds__(256) void bn_apply_k(const unsigned short* __restrict__ m,
                                                  const float* __restrict__ stats_part,
                                                  const float* __restrict__ gamma,
                                                  const float* __restrict__ beta,
                                                  float invN,
                                                  unsigned short* __restrict__ h) {
    __shared__ float ls[256];
    __shared__ float4 caf[32], cbf[32];
    int tid = threadIdx.x;
    float s = 0.f;
    for (int p = 0; p < NSPLIT; p++) s += stats_part[p * 256 + tid];
    ls[tid] = s;
    __syncthreads();
    if (tid < 128) {
        float mu = ls[tid] * invN;
        float var = ls[128 + tid] * invN - mu * mu;
        float a = gamma[tid] * rsqrtf(var + 1e-5f);
        ((float*)caf)[tid] = a;
        ((float*)cbf)[tid] = beta[tid] - mu * a;
    }
    __syncthreads();

    int t0 = blockIdx.x * 256 + tid;
    float4 a = caf[t0 & 31];
    float4 b = cbf[t0 & 31];
    for (int t = t0; t < NN * 32; t += 2048 * 256) {
        ushort4 mv = ((const ushort4*)m)[t];
        ushort4 hv = ((const ushort4*)h)[t];
        float h0 = bf2f(hv.x) + fmaxf(bf2f(mv.x) * a.x + b.x, 0.f);
        float h1 = bf2f(hv.y) + fmaxf(bf2f(mv.y) * a.y + b.y, 0.f);
        float h2 = bf2f(hv.z) + fmaxf(bf2f(mv.z) * a.z + b.z, 0.f);
        float h3 = bf2f(hv.w) + fmaxf(bf2f(mv.w) * a.w + b.w, 0.f);
        ushort4 o;
        o.x = f2bf(h0); o.y = f2bf(h1); o.z = f2bf(h2); o.w = f2bf(h3);
        ((ushort4*)h)[t] = o;
    }
}

// C[M,128] = op(bf16 A[M,128] @ Wf + bias)
template <bool RELU, bool OBF16>
__global__ __launch_bounds__(256) void gemm128f(const unsigned short* __restrict__ A,
                                                const unsigned short* __restrict__ Wf,
                                                const float* __restrict__ bias,
                                                void* __restrict__ Cv, int ldC, int M) {
    __shared__ short Wlds[16384];
    int tid = threadIdx.x;
#pragma unroll
    for (int i = 0; i < 8; i++) {
        int flat = i * 256 + tid;
        ((bf16x8*)Wlds)[flat] = ((const bf16x8*)Wf)[flat];
    }
    __syncthreads();

    int w = tid >> 6, lane = tid & 63;
    int quad = lane >> 4, lr = lane & 15;
    int rowA = blockIdx.x * 64 + w * 16 + lr;
    bool rowOK = rowA < M;
    const unsigned short* ap = A + (size_t)rowA * 128 + quad * 8;

    f32x4 acc[8];
#pragma unroll
    for (int c = 0; c < 8; c++) acc[c] = (f32x4){0.f, 0.f, 0.f, 0.f};
#pragma unroll
    for (int kk = 0; kk < 4; kk++) {
        bf16x8 af = rowOK ? *(const bf16x8*)(ap + kk * 32)
                          : (bf16x8){0, 0, 0, 0, 0, 0, 0, 0};
#pragma unroll
        for (int c = 0; c < 8; c++) {
            bf16x8 bf = ((const bf16x8*)Wlds)[(c * 4 + kk) * 64 + lane];
            acc[c] = __builtin_amdgcn_mfma_f32_16x16x32_bf16(af, bf, acc[c], 0, 0, 0);
        }
    }

    int r0 = blockIdx.x * 64 + w * 16 + quad * 4;
#pragma unroll
    for (int c = 0; c < 8; c++) {
        int col = c * 16 + lr;
        float bv = bias[col];
#pragma unroll
        for (int r = 0; r < 4; r++) {
            int row = r0 + r;
            if (row < M) {
                float v = acc[c][r] + bv;
                if (RELU) v = fmaxf(v, 0.f);
                if (OBF16)
                    ((unsigned short*)Cv)[(size_t)row * ldC + col] = f2bf(v);
                else
                    ((float*)Cv)[(size_t)row * ldC + col] = v;
            }
        }
    }
}

// both Wo2 halves in one launch: blocks [0,79) half 0, [79,158) half 1
__global__ __launch_bounds__(256) void outproj2_k(const unsigned short* __restrict__ A,
                                                  const unsigned short* __restrict__ WfB,
                                                  const float* __restrict__ bo2,
                                                  float* __restrict__ out) {
    __shared__ short Wlds[16384];
    int half = blockIdx.x >= 79;
    int blk = blockIdx.x - half * 79;
    const unsigned short* Wf = WfB + half * 16384;
    int tid = threadIdx.x;
#pragma unroll
    for (int i = 0; i < 8; i++) {
        int flat = i * 256 + tid;
        ((bf16x8*)Wlds)[flat] = ((const bf16x8*)Wf)[flat];
    }
    __syncthreads();

    int w = tid >> 6, lane = tid & 63;
    int quad = lane >> 4, lr = lane & 15;
    int rowA = blk * 64 + w * 16 + lr;
    bool rowOK = rowA < NG;
    const unsigned short* ap = A + (size_t)rowA * 128 + quad * 8;

    f32x4 acc[8];
#pragma unroll
    for (int c = 0; c < 8; c++) acc[c] = (f32x4){0.f, 0.f, 0.f, 0.f};
#pragma unroll
    for (int kk = 0; kk < 4; kk++) {
        bf16x8 af = rowOK ? *(const bf16x8*)(ap + kk * 32)
                          : (bf16x8){0, 0, 0, 0, 0, 0, 0, 0};
#pragma unroll
        for (int c = 0; c < 8; c++) {
            bf16x8 bf = ((const bf16x8*)Wlds)[(c * 4 + kk) * 64 + lane];
            acc[c] = __builtin_amdgcn_mfma_f32_16x16x32_bf16(af, bf, acc[c], 0, 0, 0);
        }
    }

    int r0 = blk * 64 + w * 16 + quad * 4;
#pragma unroll
    for (int c = 0; c < 8; c++) {
        int col = half * 128 + c * 16 + lr;
        float bv = bo2[col];
#pragma unroll
        for (int r = 0; r < 4; r++) {
            int row = r0 + r;
            if (row < NG) out[(size_t)row * 256 + col] = acc[c][r] + bv;
        }
    }
}

// one block per graph: mean over its node rows -> bf16 pooled
__global__ __launch_bounds__(128) void pool_k(const unsigned short* __restrict__ h,
                                              const int* __restrict__ gstart,
                                              unsigned short* __restrict__ pooled) {
    int g = blockIdx.x, col = threadIdx.x;
    int r0 = gstart[g], r1 = gstart[g + 1];
    float s = 0.f;
    for (int r = r0; r < r1; r++) s += bf2f(h[(size_t)r * H + col]);
    pooled[(size_t)g * H + col] = f2bf(s / fmaxf((float)(r1 - r0), 1.f));
}

extern "C" void kernel_launch(void* const* d_in, const int* in_sizes, int n_in,
                              void* d_out, int out_size, void* d_ws, size_t ws_size,
                              hipStream_t stream) {
    const float* x     = (const float*)d_in[0];
    const int*   ei    = (const int*)d_in[1];
    const int*   batch = (const int*)d_in[2];
    const float* Wn    = (const float*)d_in[3];
    const float* bn_b  = (const float*)d_in[4];
    const float* eps   = (const float*)d_in[5];
    const float* W1    = (const float*)d_in[6];
    const float* b1    = (const float*)d_in[7];
    const float* W2    = (const float*)d_in[8];
    const float* b2    = (const float*)d_in[9];
    const float* gamma = (const float*)d_in[10];
    const float* beta  = (const float*)d_in[11];
    const float* Wo1   = (const float*)d_in[12];
    const float* bo1   = (const float*)d_in[13];
    const float* Wo2   = (const float*)d_in[14];
    const float* bo2   = (const float*)d_in[15];
    float* out = (float*)d_out;

    // ---- workspace: ~120 MB ----
    unsigned short* h    = (unsigned short*)d_ws;                  // NN*H bf16
    unsigned short* m    = h + (size_t)NN * H;                     // NN*H bf16
    unsigned short* aggB = m + (size_t)NN * H;                     // NN*H bf16
    unsigned short* tB   = aggB + (size_t)NN * H;                  // NG*H bf16
    float* stats_part    = (float*)(tB + (size_t)NG * H);          // NSPLIT*256
    float* coef          = stats_part + NSPLIT * 256;              // 256 (unused, pad)
    unsigned short* Wf   = (unsigned short*)(coef + 256);          // 11*16384 bf16
    unsigned short* pooledB = Wf + 11 * 16384;                     // NG*H bf16
    int* offsets = (int*)(pooledB + (size_t)NG * H);               // NOFF
    int* adj     = offsets + NOFF;                                 // NE
    int* gstart  = adj + NE;                                       // NG+1
    // transient CSR-build arrays overlaid in m (first written by layer-0 mlp_k)
    int* deg    = (int*)m;         // NN
    int* part   = deg + NN;        // NOFF
    int* bsum   = part + NOFF;     // 256
    int* cursor = bsum + 256;      // NN

    setup_k<<<597, 256, 0, stream>>>(batch, W1, W2, Wo1, Wo2, deg, gstart, Wf);
    hist_k<<<2344, 256, 0, stream>>>(ei, deg);
    scan1_k<<<NBLK, 256, 0, stream>>>(deg, part, bsum);
    scan2_k<<<1, 256, 0, stream>>>(bsum);
    scan3_k<<<NBLK, 256, 0, stream>>>(part, bsum, offsets, cursor);
    fill_k<<<2344, 256, 0, stream>>>(ei, cursor, adj);

    encoder_k<<<18750, 256, 0, stream>>>(x, Wn, bn_b, h);

    for (int l = 0; l < 4; l++) {
        gather_k<<<9375, 256, 0, stream>>>(h, offsets, adj, eps, l, aggB, stats_part);
        mlp_k<<<2344, 256, 0, stream>>>(aggB, Wf + l * 16384, Wf + (4 + l) * 16384,
                                        b1 + l * 128, b2 + l * 128, m, NN, stats_part);
        bn_apply_k<<<2048, 256, 0, stream>>>(m, stats_part, gamma + l * 128,
                                             beta + l * 128, 1.f / NN, h);
    }

    pool_k<<<NG, 128, 0, stream>>>(h, gstart, pooledB);

    gemm128f<true, true><<<79, 256, 0, stream>>>(
        pooledB, Wf + 8 * 16384, bo1, tB, 128, NG);
    outproj2_k<<<158, 256, 0, stream>>>(tB, Wf + 9 * 16384, bo2, out);
}